// Round 25
// baseline (86.446 us; speedup 1.0000x reference)
//
#include <hip/hip_runtime.h>
#include <math.h>

#define NCAPS 8
#define SEQ 200
#define EMB 128
#define CDIM 64
#define NROUNDS 3
#define BPAD 68    // row base bank-quad = 17l%32 (coprime) -> conflict-free patterns
#define CPAD 68

typedef __bf16 bf16x8 __attribute__((ext_vector_type(8)));
typedef float f32x4 __attribute__((ext_vector_type(4)));
typedef unsigned short ushort8 __attribute__((ext_vector_type(8)));
typedef unsigned short ushort4v __attribute__((ext_vector_type(4)));

__device__ __forceinline__ float4 ld4(const float* p) { return *reinterpret_cast<const float4*>(p); }
__device__ __forceinline__ void st4(float* p, float4 v) { *reinterpret_cast<float4*>(p) = v; }
__device__ __forceinline__ float bf2f(unsigned short b) {
  unsigned u = ((unsigned)b) << 16;
  return __builtin_bit_cast(float, u);
}
// split a float4-pair into bf16 hi/lo fragments
__device__ __forceinline__ void split8(float4 u0, float4 u1, bf16x8& h, bf16x8& lo) {
  float a[8] = {u0.x, u0.y, u0.z, u0.w, u1.x, u1.y, u1.z, u1.w};
#pragma unroll
  for (int j = 0; j < 8; ++j) {
    h[j] = (__bf16)a[j];
    lo[j] = (__bf16)(a[j] - (float)h[j]);
  }
}
// plain bf16 convert (no lo)
__device__ __forceinline__ bf16x8 cvt8(float4 u0, float4 u1) {
  bf16x8 h;
  h[0] = (__bf16)u0.x; h[1] = (__bf16)u0.y; h[2] = (__bf16)u0.z; h[3] = (__bf16)u0.w;
  h[4] = (__bf16)u1.x; h[5] = (__bf16)u1.y; h[6] = (__bf16)u1.z; h[7] = (__bf16)u1.w;
  return h;
}

// Projection GEMM v7 (R25): R23's proven config (LDS S-table, 2 tiles/wave,
// (256,2) = calibrated spill-free 128-reg slot, 2-term MFMA) with the S
// hi/lo split computed IN-KERNEL from raw S (deletes the split_S launch).
// Fragment layout: element (e,d) -> fi=(e>>5)*4+(d>>4), ln=((e>>3)&3)*16+(d&15), j=e&7.
__global__ __launch_bounds__(256, 2) void proj_kernel(
    const float* __restrict__ A,
    const float* __restrict__ S,               // [128][64] raw fp32
    unsigned short* __restrict__ behG16,
    int Mtot)
{
  __shared__ ushort8 sF[2048];   // 32 KB: hi[0..1023], lo[1024..2047]
  const int t = threadIdx.x;
  const int lane = t & 63;
  const int w = t >> 6;
  const int fr = lane & 15;     // beh row-in-tile (B-operand col); C col
  const int kg = lane >> 4;     // k-group 0..3; C row-quad
  for (int i = t; i < EMB * CDIM; i += 256) {
    int e = i >> 6, d = i & 63;
    float v = S[i];
    __bf16 hb = (__bf16)v;
    __bf16 lb = (__bf16)(v - (float)hb);
    int fi = (e >> 5) * 4 + (d >> 4);
    int ln = (((e >> 3) & 3) << 4) + (d & 15);
    int j = e & 7;
    ((unsigned short*)&sF[fi * 64 + ln])[j] = __builtin_bit_cast(unsigned short, hb);
    ((unsigned short*)&sF[1024 + fi * 64 + ln])[j] = __builtin_bit_cast(unsigned short, lb);
  }
  __syncthreads();

#pragma unroll
  for (int rt = 0; rt < 2; ++rt) {
    const int r0 = blockIdx.x * 128 + (w * 2 + rt) * 16;
    const int row = r0 + fr;
    const bool ok = (row < Mtot);
    const float* arow = A + (size_t)row * EMB + kg * 8;

    f32x4 acc[4];
#pragma unroll
    for (int ct = 0; ct < 4; ++ct) acc[ct] = (f32x4){0.f, 0.f, 0.f, 0.f};

#pragma unroll
    for (int ks = 0; ks < 4; ++ks) {
      bf16x8 aH;
      if (ok) {
        aH = cvt8(ld4(arow + ks * 32), ld4(arow + ks * 32 + 4));
      } else {
#pragma unroll
        for (int j = 0; j < 8; ++j) aH[j] = (__bf16)0.f;
      }
#pragma unroll
      for (int ct = 0; ct < 4; ++ct) {
        bf16x8 sH = __builtin_bit_cast(bf16x8, sF[(ks * 4 + ct) * 64 + lane]);
        bf16x8 sL = __builtin_bit_cast(bf16x8, sF[1024 + (ks * 4 + ct) * 64 + lane]);
        // swapped: A-operand = S (rows=d), B-operand = beh rows (cols=l)
        acc[ct] = __builtin_amdgcn_mfma_f32_16x16x32_bf16(sH, aH, acc[ct], 0, 0, 0);
        acc[ct] = __builtin_amdgcn_mfma_f32_16x16x32_bf16(sL, aH, acc[ct], 0, 0, 0);
      }
    }
#pragma unroll
    for (int ct = 0; ct < 4; ++ct) {
      if (ok) {
        ushort4v o;
        o[0] = __builtin_bit_cast(unsigned short, (__bf16)acc[ct][0]);
        o[1] = __builtin_bit_cast(unsigned short, (__bf16)acc[ct][1]);
        o[2] = __builtin_bit_cast(unsigned short, (__bf16)acc[ct][2]);
        o[3] = __builtin_bit_cast(unsigned short, (__bf16)acc[ct][3]);
        *reinterpret_cast<ushort4v*>(&behG16[(size_t)row * CDIM + ct * 16 + kg * 4]) = o;
      }
    }
  }
}

// Routing (R20/R23-proven, byte-identical): Phase A softmax, Phase B
// l-partitioned, Phase C squash, Phase D MFMA split-bf16.
__global__ __launch_bounds__(512, 4) void route_kernel(
    const unsigned short* __restrict__ behG16, // [B][200][64] bf16
    const unsigned char* __restrict__ maskraw, // bool/int32/float32 (detected)
    const float* __restrict__ B0,              // [8][200]
    float* __restrict__ out)                   // [B][8][64]
{
  __shared__ float sBeh[SEQ][BPAD];        // 54.4 KB (fp32)
  __shared__ float sB[NCAPS][SEQ];         // 6.4 KB
  __shared__ float sWt[SEQ][NCAPS];        // 6.4 KB
  __shared__ float sCaps[NCAPS][CPAD];     // 2.2 KB
  __shared__ float sPart[4][NCAPS][CDIM];  // 8.0 KB
  __shared__ float sMask[SEQ];             // 0.8 KB
  __shared__ int sFlagA, sFlagB;

  const int b = blockIdx.x;
  const int t = threadIdx.x;
  const int lane = t & 63;
  const int w = t >> 6;

  // ---- detect mask dtype over first 1KB ----
  if (t == 0) { sFlagA = 0; sFlagB = 0; }
  __syncthreads();
  for (int i = t; i < 1024; i += 512) {
    unsigned char v = maskraw[i];
    if (v != 0) {
      int m = i & 3;
      if (m == 1) atomicOr(&sFlagA, 1);
      else if (m >= 2) atomicOr(&sFlagB, 1);
    }
  }
  __syncthreads();
  const int mode = sFlagA ? 1 : (sFlagB ? 2 : 0);

  // ---- load mask, B0, and stage beh (bf16 -> fp32) ----
  if (mode == 1) {
    for (int i = t; i < SEQ; i += 512)
      sMask[i] = maskraw[(size_t)b * SEQ + i] ? 1.0f : 0.0f;
  } else if (mode == 2) {
    const float* mf = (const float*)maskraw;
    for (int i = t; i < SEQ; i += 512)
      sMask[i] = (mf[(size_t)b * SEQ + i] != 0.0f) ? 1.0f : 0.0f;
  } else {
    const int* mi = (const int*)maskraw;
    for (int i = t; i < SEQ; i += 512)
      sMask[i] = mi[(size_t)b * SEQ + i] ? 1.0f : 0.0f;
  }
  for (int i = t; i < NCAPS * SEQ; i += 512)
    (&sB[0][0])[i] = B0[i];
  for (int i = t; i < SEQ * 8; i += 512) {
    int l = i >> 3, d8 = (i & 7) * 8;
    ushort8 u = *reinterpret_cast<const ushort8*>(
        behG16 + ((size_t)b * SEQ + l) * CDIM + d8);
    st4(&sBeh[l][d8], make_float4(bf2f(u[0]), bf2f(u[1]), bf2f(u[2]), bf2f(u[3])));
    st4(&sBeh[l][d8 + 4], make_float4(bf2f(u[4]), bf2f(u[5]), bf2f(u[6]), bf2f(u[7])));
  }
  __syncthreads();

  // ---- routing rounds ----
  for (int round = 0; round < NROUNDS; ++round) {
    // Phase A: masked softmax; wave w owns capsule k=w; writes TRANSPOSED sWt[l][k].
    {
      const int k = w;
      float v0 = sB[k][lane],       f0 = sMask[lane];
      float v1 = sB[k][lane + 64],  f1 = sMask[lane + 64];
      float v2 = sB[k][lane + 128], f2 = sMask[lane + 128];
      float v3 = 0.f, f3 = 0.f;
      if (lane < SEQ - 192) { v3 = sB[k][lane + 192]; f3 = sMask[lane + 192]; }
      float m = -3.402823466e38f;
      if (f0 > 0.f) m = fmaxf(m, v0);
      if (f1 > 0.f) m = fmaxf(m, v1);
      if (f2 > 0.f) m = fmaxf(m, v2);
      if (f3 > 0.f) m = fmaxf(m, v3);
#pragma unroll
      for (int off = 32; off >= 1; off >>= 1) m = fmaxf(m, __shfl_xor(m, off));
      float e0 = (f0 > 0.f) ? __expf(v0 - m) : 0.f;
      float e1 = (f1 > 0.f) ? __expf(v1 - m) : 0.f;
      float e2 = (f2 > 0.f) ? __expf(v2 - m) : 0.f;
      float e3 = (f3 > 0.f) ? __expf(v3 - m) : 0.f;
      float s = ((e0 + e1) + (e2 + e3));
#pragma unroll
      for (int off = 32; off >= 1; off >>= 1) s += __shfl_xor(s, off);
      float inv = (s > 0.f) ? (1.0f / s) : 0.f;
      sWt[lane][k] = e0 * inv;
      sWt[lane + 64][k] = e1 * inv;
      sWt[lane + 128][k] = e2 * inv;
      if (lane < SEQ - 192) sWt[lane + 192][k] = e3 * inv;
    }
    __syncthreads();

    // Phase B (l-partitioned): wave w scans l = w+8i (25 rows) for ALL 8 caps.
    float vcap;
    {
      float p0 = 0.f, p1 = 0.f, p2 = 0.f, p3 = 0.f;
      float p4 = 0.f, p5 = 0.f, p6 = 0.f, p7 = 0.f;
      for (int i = 0; i < 25; ++i) {
        const int l = w + 8 * i;
        float bv = sBeh[l][lane];
        float4 wa = ld4(&sWt[l][0]);
        float4 wb = ld4(&sWt[l][4]);
        p0 = fmaf(wa.x, bv, p0); p1 = fmaf(wa.y, bv, p1);
        p2 = fmaf(wa.z, bv, p2); p3 = fmaf(wa.w, bv, p3);
        p4 = fmaf(wb.x, bv, p4); p5 = fmaf(wb.y, bv, p5);
        p6 = fmaf(wb.z, bv, p6); p7 = fmaf(wb.w, bv, p7);
      }
      if (w < 4) {
        sPart[w][0][lane] = p0; sPart[w][1][lane] = p1;
        sPart[w][2][lane] = p2; sPart[w][3][lane] = p3;
        sPart[w][4][lane] = p4; sPart[w][5][lane] = p5;
        sPart[w][6][lane] = p6; sPart[w][7][lane] = p7;
      }
      __syncthreads();
      if (w >= 4) {
        const int u = w - 4;
        sPart[u][0][lane] += p0; sPart[u][1][lane] += p1;
        sPart[u][2][lane] += p2; sPart[u][3][lane] += p3;
        sPart[u][4][lane] += p4; sPart[u][5][lane] += p5;
        sPart[u][6][lane] += p6; sPart[u][7][lane] += p7;
      }
      __syncthreads();
      vcap = (sPart[0][w][lane] + sPart[1][w][lane]) +
             (sPart[2][w][lane] + sPart[3][w][lane]);
    }

    // Phase C: squash in-wave
    {
      float q = vcap * vcap;
#pragma unroll
      for (int off = 32; off >= 1; off >>= 1) q += __shfl_xor(q, off);
      float n = sqrtf(q);
      float f = (q > 0.f) ? (q / ((1.0f + q) * n)) : 0.f;
      vcap *= f;
      sCaps[w][lane] = vcap;
      if (round == NROUNDS - 1)
        out[((size_t)b * NCAPS + w) * CDIM + lane] = vcap;
    }
    __syncthreads();

    // Phase D (MFMA): B[8x200] += caps[8x64] @ behT[64x200].
    if (round < NROUNDS - 1) {
      const int fr = lane & 15;
      const int kg = lane >> 4;
      bf16x8 aH[2], aL[2];
#pragma unroll
      for (int ks = 0; ks < 2; ++ks) {
        if (fr < NCAPS) {
          split8(ld4(&sCaps[fr][ks * 32 + kg * 8]),
                 ld4(&sCaps[fr][ks * 32 + kg * 8 + 4]), aH[ks], aL[ks]);
        } else {
          bf16x8 z;
#pragma unroll
          for (int j = 0; j < 8; ++j) z[j] = (__bf16)0.f;
          aH[ks] = z; aL[ks] = z;
        }
      }
      for (int lt = w; lt < 13; lt += 8) {
        const int l = lt * 16 + fr;
        const int lc = (l < SEQ) ? l : (SEQ - 1);
        f32x4 acc = {0.f, 0.f, 0.f, 0.f};
#pragma unroll
        for (int ks = 0; ks < 2; ++ks) {
          bf16x8 bh, bl;
          split8(ld4(&sBeh[lc][ks * 32 + kg * 8]),
                 ld4(&sBeh[lc][ks * 32 + kg * 8 + 4]), bh, bl);
          acc = __builtin_amdgcn_mfma_f32_16x16x32_bf16(aH[ks], bh, acc, 0, 0, 0);
          acc = __builtin_amdgcn_mfma_f32_16x16x32_bf16(aL[ks], bh, acc, 0, 0, 0);
          acc = __builtin_amdgcn_mfma_f32_16x16x32_bf16(aH[ks], bl, acc, 0, 0, 0);
        }
        if (kg < 2 && l < SEQ) {
#pragma unroll
          for (int reg = 0; reg < 4; ++reg)
            sB[kg * 4 + reg][l] += acc[reg];
        }
      }
    }
    __syncthreads();
  }
}

// Fallback (ws too small): fused single-sample kernel (R7 structure).
__global__ __launch_bounds__(512, 2) void mie1_kernel(
    const float* __restrict__ behaviors,
    const unsigned char* __restrict__ maskraw,
    const float* __restrict__ S,
    const float* __restrict__ B0,
    float* __restrict__ out)
{
  __shared__ float sBeh[SEQ][68];
  __shared__ float sB[NCAPS][SEQ];
  __shared__ float sW[NCAPS][SEQ];
  __shared__ float sCaps[NCAPS][CPAD];
  __shared__ float sMask[SEQ];
  __shared__ int sFlagA, sFlagB;
  __shared__ ushort8 sSfH[16 * 64];
  __shared__ ushort8 sSfL[16 * 64];

  const int b = blockIdx.x;
  const int t = threadIdx.x;
  const int lane = t & 63;
  const int w = t >> 6;

  if (t == 0) { sFlagA = 0; sFlagB = 0; }
  __syncthreads();
  for (int i = t; i < 1024; i += 512) {
    unsigned char v = maskraw[i];
    if (v != 0) {
      int m = i & 3;
      if (m == 1) atomicOr(&sFlagA, 1);
      else if (m >= 2) atomicOr(&sFlagB, 1);
    }
  }
  __syncthreads();
  const int mode = sFlagA ? 1 : (sFlagB ? 2 : 0);

  if (mode == 1) {
    for (int i = t; i < SEQ; i += 512)
      sMask[i] = maskraw[(size_t)b * SEQ + i] ? 1.0f : 0.0f;
  } else if (mode == 2) {
    const float* mf = (const float*)maskraw;
    for (int i = t; i < SEQ; i += 512)
      sMask[i] = (mf[(size_t)b * SEQ + i] != 0.0f) ? 1.0f : 0.0f;
  } else {
    const int* mi = (const int*)maskraw;
    for (int i = t; i < SEQ; i += 512)
      sMask[i] = mi[(size_t)b * SEQ + i] ? 1.0f : 0.0f;
  }
  for (int i = t; i < NCAPS * SEQ; i += 512)
    (&sB[0][0])[i] = B0[i];
  for (int i = t; i < EMB * CDIM; i += 512) {
    int e = i >> 6, d = i & 63;
    float v = S[i];
    __bf16 hb = (__bf16)v;
    __bf16 lb = (__bf16)(v - (float)hb);
    int fi = (e >> 5) * 4 + (d >> 4);
    int ln = (((e >> 3) & 3) << 4) + (d & 15);
    int j = e & 7;
    ((unsigned short*)&sSfH[fi * 64 + ln])[j] = __builtin_bit_cast(unsigned short, hb);
    ((unsigned short*)&sSfL[fi * 64 + ln])[j] = __builtin_bit_cast(unsigned short, lb);
  }
  __syncthreads();

  {
    const int fr = lane & 15;
    const int kg = lane >> 4;
    for (int rt = w; rt < 13; rt += 8) {
      const int r0 = rt * 16;
      const int row = r0 + fr;
      const float* arow = behaviors + ((size_t)b * SEQ + row) * EMB + kg * 8;
      f32x4 acc[4];
#pragma unroll
      for (int ct = 0; ct < 4; ++ct) acc[ct] = (f32x4){0.f, 0.f, 0.f, 0.f};
#pragma unroll
      for (int ks = 0; ks < 4; ++ks) {
        bf16x8 aH, aL;
        if (row < SEQ) {
          split8(ld4(arow + ks * 32), ld4(arow + ks * 32 + 4), aH, aL);
        } else {
#pragma unroll
          for (int j = 0; j < 8; ++j) { aH[j] = (__bf16)0.f; aL[j] = (__bf16)0.f; }
        }
#pragma unroll
        for (int ct = 0; ct < 4; ++ct) {
          bf16x8 sH = __builtin_bit_cast(bf16x8, sSfH[(ks * 4 + ct) * 64 + lane]);
          bf16x8 sL = __builtin_bit_cast(bf16x8, sSfL[(ks * 4 + ct) * 64 + lane]);
          acc[ct] = __builtin_amdgcn_mfma_f32_16x16x32_bf16(aH, sH, acc[ct], 0, 0, 0);
          acc[ct] = __builtin_amdgcn_mfma_f32_16x16x32_bf16(aL, sH, acc[ct], 0, 0, 0);
          acc[ct] = __builtin_amdgcn_mfma_f32_16x16x32_bf16(aH, sL, acc[ct], 0, 0, 0);
        }
      }
#pragma unroll
      for (int ct = 0; ct < 4; ++ct) {
#pragma unroll
        for (int reg = 0; reg < 4; ++reg) {
          int orow = r0 + kg * 4 + reg;
          if (orow < SEQ) sBeh[orow][ct * 16 + fr] = acc[ct][reg];
        }
      }
    }
  }
  __syncthreads();

  for (int round = 0; round < NROUNDS; ++round) {
    {
      const int k = w;
      float v0 = sB[k][lane],       f0 = sMask[lane];
      float v1 = sB[k][lane + 64],  f1 = sMask[lane + 64];
      float v2 = sB[k][lane + 128], f2 = sMask[lane + 128];
      float v3 = 0.f, f3 = 0.f;
      if (lane < SEQ - 192) { v3 = sB[k][lane + 192]; f3 = sMask[lane + 192]; }
      float m = -3.402823466e38f;
      if (f0 > 0.f) m = fmaxf(m, v0);
      if (f1 > 0.f) m = fmaxf(m, v1);
      if (f2 > 0.f) m = fmaxf(m, v2);
      if (f3 > 0.f) m = fmaxf(m, v3);
#pragma unroll
      for (int off = 32; off >= 1; off >>= 1) m = fmaxf(m, __shfl_xor(m, off));
      float e0 = (f0 > 0.f) ? __expf(v0 - m) : 0.f;
      float e1 = (f1 > 0.f) ? __expf(v1 - m) : 0.f;
      float e2 = (f2 > 0.f) ? __expf(v2 - m) : 0.f;
      float e3 = (f3 > 0.f) ? __expf(v3 - m) : 0.f;
      float s = ((e0 + e1) + (e2 + e3));
#pragma unroll
      for (int off = 32; off >= 1; off >>= 1) s += __shfl_xor(s, off);
      float inv = (s > 0.f) ? (1.0f / s) : 0.f;
      sW[k][lane] = e0 * inv;
      sW[k][lane + 64] = e1 * inv;
      sW[k][lane + 128] = e2 * inv;
      if (lane < SEQ - 192) sW[k][lane + 192] = e3 * inv;
    }
    __syncthreads();
    {
      float a0 = 0.f, a1 = 0.f, a2 = 0.f, a3 = 0.f;
#pragma unroll 2
      for (int l = 0; l < SEQ; l += 4) {
        a0 = fmaf(sW[w][l + 0], sBeh[l + 0][lane], a0);
        a1 = fmaf(sW[w][l + 1], sBeh[l + 1][lane], a1);
        a2 = fmaf(sW[w][l + 2], sBeh[l + 2][lane], a2);
        a3 = fmaf(sW[w][l + 3], sBeh[l + 3][lane], a3);
      }
      float v = (a0 + a1) + (a2 + a3);
      float q = v * v;
#pragma unroll
      for (int off = 32; off >= 1; off >>= 1) q += __shfl_xor(q, off);
      float n = sqrtf(q);
      float f = (q > 0.f) ? (q / ((1.0f + q) * n)) : 0.f;
      v *= f;
      sCaps[w][lane] = v;
      if (round == NROUNDS - 1)
        out[((size_t)b * NCAPS + w) * CDIM + lane] = v;
    }
    __syncthreads();
    if (round < NROUNDS - 1) {
      const int k = t & 7;
      for (int oi = t; oi < NCAPS * SEQ; oi += 512) {
        int l = oi >> 3;
        float px = 0.f, py = 0.f, pz = 0.f, pw = 0.f;
#pragma unroll 4
        for (int i = 0; i < 16; ++i) {
          float4 cp = ld4(&sCaps[k][i * 4]);
          float4 b4 = ld4(&sBeh[l][i * 4]);
          px = fmaf(cp.x, b4.x, px);
          py = fmaf(cp.y, b4.y, py);
          pz = fmaf(cp.z, b4.z, pz);
          pw = fmaf(cp.w, b4.w, pw);
        }
        sB[k][l] += (px + py) + (pz + pw);
      }
    }
    __syncthreads();
  }
}

extern "C" void kernel_launch(void* const* d_in, const int* in_sizes, int n_in,
                              void* d_out, int out_size, void* d_ws, size_t ws_size,
                              hipStream_t stream) {
  const float* behaviors = (const float*)d_in[0];
  const unsigned char* maskraw = (const unsigned char*)d_in[1];
  const float* S = (const float*)d_in[2];
  const float* B0 = (const float*)d_in[3];
  float* out = (float*)d_out;
  const int B = in_sizes[0] / (SEQ * EMB);
  const int Mtot = B * SEQ;
  const size_t beh_bytes = (size_t)Mtot * CDIM * sizeof(unsigned short);      // ~26.2 MB
  if (ws_size >= beh_bytes) {
    unsigned short* behG16 = (unsigned short*)d_ws;
    proj_kernel<<<dim3((Mtot + 127) / 128), dim3(256), 0, stream>>>(behaviors, S, behG16, Mtot);
    route_kernel<<<dim3(B), dim3(512), 0, stream>>>(behG16, maskraw, B0, out);
  } else {
    mie1_kernel<<<dim3(B), dim3(512), 0, stream>>>(behaviors, maskraw, S, B0, out);
  }
}

// Round 26
// 72.248 us; speedup vs baseline: 1.1965x; 1.1965x over previous
//
#include <hip/hip_runtime.h>
#include <math.h>

#define NCAPS 8
#define SEQ 200
#define EMB 128
#define CDIM 64
#define NROUNDS 3
#define BPAD 68    // row base bank-quad = 4l%32 -> conflict-free row/col patterns
#define CPAD 68

typedef __bf16 bf16x8 __attribute__((ext_vector_type(8)));
typedef float f32x4 __attribute__((ext_vector_type(4)));
typedef unsigned short ushort8 __attribute__((ext_vector_type(8)));
typedef unsigned short ushort4v __attribute__((ext_vector_type(4)));

__device__ __forceinline__ float4 ld4(const float* p) { return *reinterpret_cast<const float4*>(p); }
__device__ __forceinline__ void st4(float* p, float4 v) { *reinterpret_cast<float4*>(p) = v; }
__device__ __forceinline__ float bf2f(unsigned short b) {
  unsigned u = ((unsigned)b) << 16;
  return __builtin_bit_cast(float, u);
}
// split a float4-pair into bf16 hi/lo fragments
__device__ __forceinline__ void split8(float4 u0, float4 u1, bf16x8& h, bf16x8& lo) {
  float a[8] = {u0.x, u0.y, u0.z, u0.w, u1.x, u1.y, u1.z, u1.w};
#pragma unroll
  for (int j = 0; j < 8; ++j) {
    h[j] = (__bf16)a[j];
    lo[j] = (__bf16)(a[j] - (float)h[j]);
  }
}
// plain bf16 convert (no lo)
__device__ __forceinline__ bf16x8 cvt8(float4 u0, float4 u1) {
  bf16x8 h;
  h[0] = (__bf16)u0.x; h[1] = (__bf16)u0.y; h[2] = (__bf16)u0.z; h[3] = (__bf16)u0.w;
  h[4] = (__bf16)u1.x; h[5] = (__bf16)u1.y; h[6] = (__bf16)u1.z; h[7] = (__bf16)u1.w;
  return h;
}

// One-time: split S (128x64 fp32) into MFMA-fragment-ordered bf16 hi/lo.
// Done ONCE in its own tiny kernel (64 blocks) — R25 proved folding this
// scatter into proj (repeated x1600 blocks) costs 2.5M LDS conflict cycles.
__global__ void split_S_kernel(const float* __restrict__ S, unsigned short* __restrict__ wsS) {
  int i = blockIdx.x * 256 + threadIdx.x;
  if (i >= EMB * CDIM) return;
  int e = i >> 6, d = i & 63;
  float v = S[i];
  __bf16 hb = (__bf16)v;
  __bf16 lb = (__bf16)(v - (float)hb);
  int fi = (e >> 5) * 4 + (d >> 4);
  int ln = (((e >> 3) & 3) << 4) + (d & 15);
  int j = e & 7;
  wsS[(fi * 64 + ln) * 8 + j] = __builtin_bit_cast(unsigned short, hb);
  wsS[EMB * CDIM + (fi * 64 + ln) * 8 + j] = __builtin_bit_cast(unsigned short, lb);
}

// Projection GEMM v6 (R23-proven, 72.34us total): LDS S-table (clean b128
// cooperative copy), 2 row-tiles/wave, launch_bounds(256,2) = the calibrated
// spill-free 128-reg slot, 2-term MFMA (A plain bf16 — validated: absmax
// unchanged at 9.77e-4 since the output is bf16 anyway; S keeps hi+lo).
__global__ __launch_bounds__(256, 2) void proj_kernel(
    const float* __restrict__ A,
    const unsigned short* __restrict__ SfG,
    unsigned short* __restrict__ behG16,
    int Mtot)
{
  __shared__ ushort8 sF[2048];   // 32 KB: hi[0..1023], lo[1024..2047]
  const int t = threadIdx.x;
  const int lane = t & 63;
  const int w = t >> 6;
  const int fr = lane & 15;     // beh row-in-tile (B-operand col); C col
  const int kg = lane >> 4;     // k-group 0..3; C row-quad
  {
    const ushort8* pf = (const ushort8*)SfG;
    for (int i = t; i < 2048; i += 256) sF[i] = pf[i];
  }
  __syncthreads();

#pragma unroll
  for (int rt = 0; rt < 2; ++rt) {
    const int r0 = blockIdx.x * 128 + (w * 2 + rt) * 16;
    const int row = r0 + fr;
    const bool ok = (row < Mtot);
    const float* arow = A + (size_t)row * EMB + kg * 8;

    f32x4 acc[4];
#pragma unroll
    for (int ct = 0; ct < 4; ++ct) acc[ct] = (f32x4){0.f, 0.f, 0.f, 0.f};

#pragma unroll
    for (int ks = 0; ks < 4; ++ks) {
      bf16x8 aH;
      if (ok) {
        aH = cvt8(ld4(arow + ks * 32), ld4(arow + ks * 32 + 4));
      } else {
#pragma unroll
        for (int j = 0; j < 8; ++j) aH[j] = (__bf16)0.f;
      }
#pragma unroll
      for (int ct = 0; ct < 4; ++ct) {
        bf16x8 sH = __builtin_bit_cast(bf16x8, sF[(ks * 4 + ct) * 64 + lane]);
        bf16x8 sL = __builtin_bit_cast(bf16x8, sF[1024 + (ks * 4 + ct) * 64 + lane]);
        // swapped: A-operand = S (rows=d), B-operand = beh rows (cols=l)
        acc[ct] = __builtin_amdgcn_mfma_f32_16x16x32_bf16(sH, aH, acc[ct], 0, 0, 0);
        acc[ct] = __builtin_amdgcn_mfma_f32_16x16x32_bf16(sL, aH, acc[ct], 0, 0, 0);
      }
    }
#pragma unroll
    for (int ct = 0; ct < 4; ++ct) {
      if (ok) {
        ushort4v o;
        o[0] = __builtin_bit_cast(unsigned short, (__bf16)acc[ct][0]);
        o[1] = __builtin_bit_cast(unsigned short, (__bf16)acc[ct][1]);
        o[2] = __builtin_bit_cast(unsigned short, (__bf16)acc[ct][2]);
        o[3] = __builtin_bit_cast(unsigned short, (__bf16)acc[ct][3]);
        *reinterpret_cast<ushort4v*>(&behG16[(size_t)row * CDIM + ct * 16 + kg * 4]) = o;
      }
    }
  }
}

// Routing (R20-proven, byte-identical): Phase A softmax, Phase B l-partitioned,
// Phase C squash, Phase D MFMA split-bf16.
__global__ __launch_bounds__(512, 4) void route_kernel(
    const unsigned short* __restrict__ behG16, // [B][200][64] bf16
    const unsigned char* __restrict__ maskraw, // bool/int32/float32 (detected)
    const float* __restrict__ B0,              // [8][200]
    float* __restrict__ out)                   // [B][8][64]
{
  __shared__ float sBeh[SEQ][BPAD];        // 54.4 KB (fp32)
  __shared__ float sB[NCAPS][SEQ];         // 6.4 KB
  __shared__ float sWt[SEQ][NCAPS];        // 6.4 KB
  __shared__ float sCaps[NCAPS][CPAD];     // 2.2 KB
  __shared__ float sPart[4][NCAPS][CDIM];  // 8.0 KB
  __shared__ float sMask[SEQ];             // 0.8 KB
  __shared__ int sFlagA, sFlagB;

  const int b = blockIdx.x;
  const int t = threadIdx.x;
  const int lane = t & 63;
  const int w = t >> 6;

  // ---- detect mask dtype over first 1KB ----
  if (t == 0) { sFlagA = 0; sFlagB = 0; }
  __syncthreads();
  for (int i = t; i < 1024; i += 512) {
    unsigned char v = maskraw[i];
    if (v != 0) {
      int m = i & 3;
      if (m == 1) atomicOr(&sFlagA, 1);
      else if (m >= 2) atomicOr(&sFlagB, 1);
    }
  }
  __syncthreads();
  const int mode = sFlagA ? 1 : (sFlagB ? 2 : 0);

  // ---- load mask, B0, and stage beh (bf16 -> fp32) ----
  if (mode == 1) {
    for (int i = t; i < SEQ; i += 512)
      sMask[i] = maskraw[(size_t)b * SEQ + i] ? 1.0f : 0.0f;
  } else if (mode == 2) {
    const float* mf = (const float*)maskraw;
    for (int i = t; i < SEQ; i += 512)
      sMask[i] = (mf[(size_t)b * SEQ + i] != 0.0f) ? 1.0f : 0.0f;
  } else {
    const int* mi = (const int*)maskraw;
    for (int i = t; i < SEQ; i += 512)
      sMask[i] = mi[(size_t)b * SEQ + i] ? 1.0f : 0.0f;
  }
  for (int i = t; i < NCAPS * SEQ; i += 512)
    (&sB[0][0])[i] = B0[i];
  for (int i = t; i < SEQ * 8; i += 512) {
    int l = i >> 3, d8 = (i & 7) * 8;
    ushort8 u = *reinterpret_cast<const ushort8*>(
        behG16 + ((size_t)b * SEQ + l) * CDIM + d8);
    st4(&sBeh[l][d8], make_float4(bf2f(u[0]), bf2f(u[1]), bf2f(u[2]), bf2f(u[3])));
    st4(&sBeh[l][d8 + 4], make_float4(bf2f(u[4]), bf2f(u[5]), bf2f(u[6]), bf2f(u[7])));
  }
  __syncthreads();

  // ---- routing rounds ----
  for (int round = 0; round < NROUNDS; ++round) {
    // Phase A: masked softmax; wave w owns capsule k=w; writes TRANSPOSED sWt[l][k].
    {
      const int k = w;
      float v0 = sB[k][lane],       f0 = sMask[lane];
      float v1 = sB[k][lane + 64],  f1 = sMask[lane + 64];
      float v2 = sB[k][lane + 128], f2 = sMask[lane + 128];
      float v3 = 0.f, f3 = 0.f;
      if (lane < SEQ - 192) { v3 = sB[k][lane + 192]; f3 = sMask[lane + 192]; }
      float m = -3.402823466e38f;
      if (f0 > 0.f) m = fmaxf(m, v0);
      if (f1 > 0.f) m = fmaxf(m, v1);
      if (f2 > 0.f) m = fmaxf(m, v2);
      if (f3 > 0.f) m = fmaxf(m, v3);
#pragma unroll
      for (int off = 32; off >= 1; off >>= 1) m = fmaxf(m, __shfl_xor(m, off));
      float e0 = (f0 > 0.f) ? __expf(v0 - m) : 0.f;
      float e1 = (f1 > 0.f) ? __expf(v1 - m) : 0.f;
      float e2 = (f2 > 0.f) ? __expf(v2 - m) : 0.f;
      float e3 = (f3 > 0.f) ? __expf(v3 - m) : 0.f;
      float s = ((e0 + e1) + (e2 + e3));
#pragma unroll
      for (int off = 32; off >= 1; off >>= 1) s += __shfl_xor(s, off);
      float inv = (s > 0.f) ? (1.0f / s) : 0.f;
      sWt[lane][k] = e0 * inv;
      sWt[lane + 64][k] = e1 * inv;
      sWt[lane + 128][k] = e2 * inv;
      if (lane < SEQ - 192) sWt[lane + 192][k] = e3 * inv;
    }
    __syncthreads();

    // Phase B (l-partitioned): wave w scans l = w+8i (25 rows) for ALL 8 caps.
    float vcap;
    {
      float p0 = 0.f, p1 = 0.f, p2 = 0.f, p3 = 0.f;
      float p4 = 0.f, p5 = 0.f, p6 = 0.f, p7 = 0.f;
      for (int i = 0; i < 25; ++i) {
        const int l = w + 8 * i;
        float bv = sBeh[l][lane];
        float4 wa = ld4(&sWt[l][0]);
        float4 wb = ld4(&sWt[l][4]);
        p0 = fmaf(wa.x, bv, p0); p1 = fmaf(wa.y, bv, p1);
        p2 = fmaf(wa.z, bv, p2); p3 = fmaf(wa.w, bv, p3);
        p4 = fmaf(wb.x, bv, p4); p5 = fmaf(wb.y, bv, p5);
        p6 = fmaf(wb.z, bv, p6); p7 = fmaf(wb.w, bv, p7);
      }
      if (w < 4) {
        sPart[w][0][lane] = p0; sPart[w][1][lane] = p1;
        sPart[w][2][lane] = p2; sPart[w][3][lane] = p3;
        sPart[w][4][lane] = p4; sPart[w][5][lane] = p5;
        sPart[w][6][lane] = p6; sPart[w][7][lane] = p7;
      }
      __syncthreads();
      if (w >= 4) {
        const int u = w - 4;
        sPart[u][0][lane] += p0; sPart[u][1][lane] += p1;
        sPart[u][2][lane] += p2; sPart[u][3][lane] += p3;
        sPart[u][4][lane] += p4; sPart[u][5][lane] += p5;
        sPart[u][6][lane] += p6; sPart[u][7][lane] += p7;
      }
      __syncthreads();
      vcap = (sPart[0][w][lane] + sPart[1][w][lane]) +
             (sPart[2][w][lane] + sPart[3][w][lane]);
    }

    // Phase C: squash in-wave
    {
      float q = vcap * vcap;
#pragma unroll
      for (int off = 32; off >= 1; off >>= 1) q += __shfl_xor(q, off);
      float n = sqrtf(q);
      float f = (q > 0.f) ? (q / ((1.0f + q) * n)) : 0.f;
      vcap *= f;
      sCaps[w][lane] = vcap;
      if (round == NROUNDS - 1)
        out[((size_t)b * NCAPS + w) * CDIM + lane] = vcap;
    }
    __syncthreads();

    // Phase D (MFMA): B[8x200] += caps[8x64] @ behT[64x200].
    if (round < NROUNDS - 1) {
      const int fr = lane & 15;
      const int kg = lane >> 4;
      bf16x8 aH[2], aL[2];
#pragma unroll
      for (int ks = 0; ks < 2; ++ks) {
        if (fr < NCAPS) {
          split8(ld4(&sCaps[fr][ks * 32 + kg * 8]),
                 ld4(&sCaps[fr][ks * 32 + kg * 8 + 4]), aH[ks], aL[ks]);
        } else {
          bf16x8 z;
#pragma unroll
          for (int j = 0; j < 8; ++j) z[j] = (__bf16)0.f;
          aH[ks] = z; aL[ks] = z;
        }
      }
      for (int lt = w; lt < 13; lt += 8) {
        const int l = lt * 16 + fr;
        const int lc = (l < SEQ) ? l : (SEQ - 1);
        f32x4 acc = {0.f, 0.f, 0.f, 0.f};
#pragma unroll
        for (int ks = 0; ks < 2; ++ks) {
          bf16x8 bh, bl;
          split8(ld4(&sBeh[lc][ks * 32 + kg * 8]),
                 ld4(&sBeh[lc][ks * 32 + kg * 8 + 4]), bh, bl);
          acc = __builtin_amdgcn_mfma_f32_16x16x32_bf16(aH[ks], bh, acc, 0, 0, 0);
          acc = __builtin_amdgcn_mfma_f32_16x16x32_bf16(aL[ks], bh, acc, 0, 0, 0);
          acc = __builtin_amdgcn_mfma_f32_16x16x32_bf16(aH[ks], bl, acc, 0, 0, 0);
        }
        if (kg < 2 && l < SEQ) {
#pragma unroll
          for (int reg = 0; reg < 4; ++reg)
            sB[kg * 4 + reg][l] += acc[reg];
        }
      }
    }
    __syncthreads();
  }
}

// Fallback (ws too small): fused single-sample kernel (R7 structure).
__global__ __launch_bounds__(512, 2) void mie1_kernel(
    const float* __restrict__ behaviors,
    const unsigned char* __restrict__ maskraw,
    const float* __restrict__ S,
    const float* __restrict__ B0,
    float* __restrict__ out)
{
  __shared__ float sBeh[SEQ][68];
  __shared__ float sB[NCAPS][SEQ];
  __shared__ float sW[NCAPS][SEQ];
  __shared__ float sCaps[NCAPS][CPAD];
  __shared__ float sMask[SEQ];
  __shared__ int sFlagA, sFlagB;
  __shared__ ushort8 sSfH[16 * 64];
  __shared__ ushort8 sSfL[16 * 64];

  const int b = blockIdx.x;
  const int t = threadIdx.x;
  const int lane = t & 63;
  const int w = t >> 6;

  if (t == 0) { sFlagA = 0; sFlagB = 0; }
  __syncthreads();
  for (int i = t; i < 1024; i += 512) {
    unsigned char v = maskraw[i];
    if (v != 0) {
      int m = i & 3;
      if (m == 1) atomicOr(&sFlagA, 1);
      else if (m >= 2) atomicOr(&sFlagB, 1);
    }
  }
  __syncthreads();
  const int mode = sFlagA ? 1 : (sFlagB ? 2 : 0);

  if (mode == 1) {
    for (int i = t; i < SEQ; i += 512)
      sMask[i] = maskraw[(size_t)b * SEQ + i] ? 1.0f : 0.0f;
  } else if (mode == 2) {
    const float* mf = (const float*)maskraw;
    for (int i = t; i < SEQ; i += 512)
      sMask[i] = (mf[(size_t)b * SEQ + i] != 0.0f) ? 1.0f : 0.0f;
  } else {
    const int* mi = (const int*)maskraw;
    for (int i = t; i < SEQ; i += 512)
      sMask[i] = mi[(size_t)b * SEQ + i] ? 1.0f : 0.0f;
  }
  for (int i = t; i < NCAPS * SEQ; i += 512)
    (&sB[0][0])[i] = B0[i];
  for (int i = t; i < EMB * CDIM; i += 512) {
    int e = i >> 6, d = i & 63;
    float v = S[i];
    __bf16 hb = (__bf16)v;
    __bf16 lb = (__bf16)(v - (float)hb);
    int fi = (e >> 5) * 4 + (d >> 4);
    int ln = (((e >> 3) & 3) << 4) + (d & 15);
    int j = e & 7;
    ((unsigned short*)&sSfH[fi * 64 + ln])[j] = __builtin_bit_cast(unsigned short, hb);
    ((unsigned short*)&sSfL[fi * 64 + ln])[j] = __builtin_bit_cast(unsigned short, lb);
  }
  __syncthreads();

  {
    const int fr = lane & 15;
    const int kg = lane >> 4;
    for (int rt = w; rt < 13; rt += 8) {
      const int r0 = rt * 16;
      const int row = r0 + fr;
      const float* arow = behaviors + ((size_t)b * SEQ + row) * EMB + kg * 8;
      f32x4 acc[4];
#pragma unroll
      for (int ct = 0; ct < 4; ++ct) acc[ct] = (f32x4){0.f, 0.f, 0.f, 0.f};
#pragma unroll
      for (int ks = 0; ks < 4; ++ks) {
        bf16x8 aH, aL;
        if (row < SEQ) {
          split8(ld4(arow + ks * 32), ld4(arow + ks * 32 + 4), aH, aL);
        } else {
#pragma unroll
          for (int j = 0; j < 8; ++j) { aH[j] = (__bf16)0.f; aL[j] = (__bf16)0.f; }
        }
#pragma unroll
        for (int ct = 0; ct < 4; ++ct) {
          bf16x8 sH = __builtin_bit_cast(bf16x8, sSfH[(ks * 4 + ct) * 64 + lane]);
          bf16x8 sL = __builtin_bit_cast(bf16x8, sSfL[(ks * 4 + ct) * 64 + lane]);
          acc[ct] = __builtin_amdgcn_mfma_f32_16x16x32_bf16(aH, sH, acc[ct], 0, 0, 0);
          acc[ct] = __builtin_amdgcn_mfma_f32_16x16x32_bf16(aL, sH, acc[ct], 0, 0, 0);
          acc[ct] = __builtin_amdgcn_mfma_f32_16x16x32_bf16(aH, sL, acc[ct], 0, 0, 0);
        }
      }
#pragma unroll
      for (int ct = 0; ct < 4; ++ct) {
#pragma unroll
        for (int reg = 0; reg < 4; ++reg) {
          int orow = r0 + kg * 4 + reg;
          if (orow < SEQ) sBeh[orow][ct * 16 + fr] = acc[ct][reg];
        }
      }
    }
  }
  __syncthreads();

  for (int round = 0; round < NROUNDS; ++round) {
    {
      const int k = w;
      float v0 = sB[k][lane],       f0 = sMask[lane];
      float v1 = sB[k][lane + 64],  f1 = sMask[lane + 64];
      float v2 = sB[k][lane + 128], f2 = sMask[lane + 128];
      float v3 = 0.f, f3 = 0.f;
      if (lane < SEQ - 192) { v3 = sB[k][lane + 192]; f3 = sMask[lane + 192]; }
      float m = -3.402823466e38f;
      if (f0 > 0.f) m = fmaxf(m, v0);
      if (f1 > 0.f) m = fmaxf(m, v1);
      if (f2 > 0.f) m = fmaxf(m, v2);
      if (f3 > 0.f) m = fmaxf(m, v3);
#pragma unroll
      for (int off = 32; off >= 1; off >>= 1) m = fmaxf(m, __shfl_xor(m, off));
      float e0 = (f0 > 0.f) ? __expf(v0 - m) : 0.f;
      float e1 = (f1 > 0.f) ? __expf(v1 - m) : 0.f;
      float e2 = (f2 > 0.f) ? __expf(v2 - m) : 0.f;
      float e3 = (f3 > 0.f) ? __expf(v3 - m) : 0.f;
      float s = ((e0 + e1) + (e2 + e3));
#pragma unroll
      for (int off = 32; off >= 1; off >>= 1) s += __shfl_xor(s, off);
      float inv = (s > 0.f) ? (1.0f / s) : 0.f;
      sW[k][lane] = e0 * inv;
      sW[k][lane + 64] = e1 * inv;
      sW[k][lane + 128] = e2 * inv;
      if (lane < SEQ - 192) sW[k][lane + 192] = e3 * inv;
    }
    __syncthreads();
    {
      float a0 = 0.f, a1 = 0.f, a2 = 0.f, a3 = 0.f;
#pragma unroll 2
      for (int l = 0; l < SEQ; l += 4) {
        a0 = fmaf(sW[w][l + 0], sBeh[l + 0][lane], a0);
        a1 = fmaf(sW[w][l + 1], sBeh[l + 1][lane], a1);
        a2 = fmaf(sW[w][l + 2], sBeh[l + 2][lane], a2);
        a3 = fmaf(sW[w][l + 3], sBeh[l + 3][lane], a3);
      }
      float v = (a0 + a1) + (a2 + a3);
      float q = v * v;
#pragma unroll
      for (int off = 32; off >= 1; off >>= 1) q += __shfl_xor(q, off);
      float n = sqrtf(q);
      float f = (q > 0.f) ? (q / ((1.0f + q) * n)) : 0.f;
      v *= f;
      sCaps[w][lane] = v;
      if (round == NROUNDS - 1)
        out[((size_t)b * NCAPS + w) * CDIM + lane] = v;
    }
    __syncthreads();
    if (round < NROUNDS - 1) {
      const int k = t & 7;
      for (int oi = t; oi < NCAPS * SEQ; oi += 512) {
        int l = oi >> 3;
        float px = 0.f, py = 0.f, pz = 0.f, pw = 0.f;
#pragma unroll 4
        for (int i = 0; i < 16; ++i) {
          float4 cp = ld4(&sCaps[k][i * 4]);
          float4 b4 = ld4(&sBeh[l][i * 4]);
          px = fmaf(cp.x, b4.x, px);
          py = fmaf(cp.y, b4.y, py);
          pz = fmaf(cp.z, b4.z, pz);
          pw = fmaf(cp.w, b4.w, pw);
        }
        sB[k][l] += (px + py) + (pz + pw);
      }
    }
    __syncthreads();
  }
}

extern "C" void kernel_launch(void* const* d_in, const int* in_sizes, int n_in,
                              void* d_out, int out_size, void* d_ws, size_t ws_size,
                              hipStream_t stream) {
  const float* behaviors = (const float*)d_in[0];
  const unsigned char* maskraw = (const unsigned char*)d_in[1];
  const float* S = (const float*)d_in[2];
  const float* B0 = (const float*)d_in[3];
  float* out = (float*)d_out;
  const int B = in_sizes[0] / (SEQ * EMB);
  const int Mtot = B * SEQ;
  const size_t sfrag_bytes = (size_t)2 * EMB * CDIM * sizeof(unsigned short); // 32 KB
  const size_t beh_bytes = (size_t)Mtot * CDIM * sizeof(unsigned short);      // ~26.2 MB
  if (ws_size >= sfrag_bytes + beh_bytes) {
    unsigned short* wsS = (unsigned short*)d_ws;
    unsigned short* behG16 = (unsigned short*)((char*)d_ws + sfrag_bytes);
    split_S_kernel<<<dim3((EMB * CDIM + 255) / 256), dim3(256), 0, stream>>>(S, wsS);
    proj_kernel<<<dim3((Mtot + 127) / 128), dim3(256), 0, stream>>>(behaviors, wsS, behG16, Mtot);
    route_kernel<<<dim3(B), dim3(512), 0, stream>>>(behG16, maskraw, B0, out);
  } else {
    mie1_kernel<<<dim3(B), dim3(512), 0, stream>>>(behaviors, maskraw, S, B0, out);
  }
}